// Round 1
// baseline (232.531 us; speedup 1.0000x reference)
//
#include <hip/hip_runtime.h>
#include <stdint.h>

// Problem constants
#define K_TOP      128
#define NBINS      4096        // top-12-bit radix histogram
#define BLOCK      256
#define CHUNK      4096        // elements owned by one block in main/collect pass
#define SORT_MAX   4096        // max candidates sorted in the select kernel (32 KiB LDS)

// ws layout (uint32 view):
//  [0]            candidate counter
//  [1]            binLo (threshold key prefix)
//  [16 .. 16+NBINS)        histogram
//  [16+NBINS .. +nchunk)   per-chunk max key
//  then (8B aligned)       candidate array of uint64 (key<<32 | ~idx)

__device__ __forceinline__ uint32_t f2key(float f) {
    uint32_t u = __float_as_uint(f);
    return (u & 0x80000000u) ? ~u : (u | 0x80000000u);
}

__global__ __launch_bounds__(BLOCK) void k_zero(uint32_t* ws, int nwords) {
    int i = blockIdx.x * BLOCK + threadIdx.x;
    if (i < nwords) ws[i] = 0u;
}

// Fused: leaky integration, no-fire outputs, radix histogram, per-chunk max key.
__global__ __launch_bounds__(BLOCK) void k_main(
    const float* __restrict__ x, const float* __restrict__ v,
    const float* __restrict__ resting,
    float* __restrict__ y, float* __restrict__ vout, float* __restrict__ rout,
    uint32_t* __restrict__ hist, uint32_t* __restrict__ chunkmax, int n)
{
    __shared__ uint32_t lhist[NBINS];
    __shared__ uint32_t lmax[BLOCK];
    for (int i = threadIdx.x; i < NBINS; i += BLOCK) lhist[i] = 0u;
    __syncthreads();

    uint32_t mymax = 0u;
    const int base = blockIdx.x * CHUNK;

#pragma unroll
    for (int it = 0; it < CHUNK / (BLOCK * 4); ++it) {
        int i = base + (it * BLOCK + threadIdx.x) * 4;
        if (i + 4 <= n) {
            float4 x4 = *reinterpret_cast<const float4*>(x + i);
            float4 v4 = *reinterpret_cast<const float4*>(v + i);
            float4 r4 = *reinterpret_cast<const float4*>(resting + i);
            float4 vo, ro;
#define DO_COMP(c)                                                   \
            {                                                        \
                float xv = x4.c, vv = v4.c, rr = r4.c;               \
                float vn = vv + (xv - vv) * 0.5f;                    \
                uint32_t key = f2key(vn);                            \
                if (key > mymax) mymax = key;                        \
                atomicAdd(&lhist[key >> 20], 1u);                    \
                bool refr = rr > 0.0f;                               \
                vo.c = refr ? 0.0f : vn;                             \
                ro.c = refr ? (rr - 1.0f) : 0.0f;                    \
            }
            DO_COMP(x) DO_COMP(y) DO_COMP(z) DO_COMP(w)
#undef DO_COMP
            *reinterpret_cast<float4*>(y + i)    = make_float4(0.f, 0.f, 0.f, 0.f);
            *reinterpret_cast<float4*>(vout + i) = vo;
            *reinterpret_cast<float4*>(rout + i) = ro;
        } else {
            // scalar tail (unused when n % 4 == 0)
            for (int j = i; j < n && j < i + 4; ++j) {
                float xv = x[j], vv = v[j], rr = resting[j];
                float vn = vv + (xv - vv) * 0.5f;
                uint32_t key = f2key(vn);
                if (key > mymax) mymax = key;
                atomicAdd(&lhist[key >> 20], 1u);
                bool refr = rr > 0.0f;
                y[j] = 0.0f;
                vout[j] = refr ? 0.0f : vn;
                rout[j] = refr ? (rr - 1.0f) : 0.0f;
            }
        }
    }

    // block max reduction
    lmax[threadIdx.x] = mymax;
    __syncthreads();
    for (int s = BLOCK / 2; s > 0; s >>= 1) {
        if (threadIdx.x < s) {
            uint32_t o = lmax[threadIdx.x + s];
            if (o > lmax[threadIdx.x]) lmax[threadIdx.x] = o;
        }
        __syncthreads();
    }
    if (threadIdx.x == 0) chunkmax[blockIdx.x] = lmax[0];

    // flush non-zero histogram bins
    for (int b = threadIdx.x; b < NBINS; b += BLOCK) {
        uint32_t c = lhist[b];
        if (c) atomicAdd(&hist[b], c);
    }
}

// Find the histogram bin containing rank-K from the top; write binLo = bin<<20.
__global__ __launch_bounds__(BLOCK) void k_thresh(const uint32_t* __restrict__ hist,
                                                  uint32_t* __restrict__ ws)
{
    __shared__ uint32_t ssum[BLOCK];
    int t = threadIdx.x;
    int hi = NBINS - t * 16;       // this thread's segment: bins [hi-16, hi), descending order
    uint32_t s = 0;
    for (int i = 0; i < 16; ++i) s += hist[hi - 1 - i];
    ssum[t] = s;
    __syncthreads();
    if (t == 0) {
        uint32_t cum = 0;
        int seg = 0;
        for (; seg < BLOCK; ++seg) {
            if (cum + ssum[seg] >= K_TOP) break;
            cum += ssum[seg];
        }
        uint32_t binLo = 0;
        if (seg < BLOCK) {
            int top = NBINS - seg * 16 - 1;
            int b = top;
            for (; b > top - 16; --b) {
                cum += hist[b];
                if (cum >= K_TOP) break;
            }
            if (b == top - 16) b = top - 15;  // safety (shouldn't happen)
            binLo = ((uint32_t)b) << 20;
        }
        ws[1] = binLo;
    }
}

// Collect candidates (key >= binLo). Chunks whose max is below threshold exit immediately.
__global__ __launch_bounds__(BLOCK) void k_collect(
    const float* __restrict__ x, const float* __restrict__ v,
    const uint32_t* __restrict__ chunkmax, const uint32_t* __restrict__ ws,
    uint64_t* __restrict__ cand, uint32_t* __restrict__ counter,
    int n, uint32_t cap)
{
    uint32_t binLo = ws[1];
    if (chunkmax[blockIdx.x] < binLo) return;
    const int base = blockIdx.x * CHUNK;
#pragma unroll
    for (int it = 0; it < CHUNK / BLOCK; ++it) {
        int i = base + it * BLOCK + threadIdx.x;
        if (i < n) {
            float vv = v[i];
            float vn = vv + (x[i] - vv) * 0.5f;
            uint32_t key = f2key(vn);
            if (key >= binLo) {
                uint32_t p = atomicAdd(counter, 1u);
                if (p < cap) cand[p] = ((uint64_t)key << 32) | (uint32_t)(~(uint32_t)i);
            }
        }
    }
}

// Sort candidates descending by (key, then lowest index); apply fire fixup for top-K.
__global__ __launch_bounds__(BLOCK) void k_select(
    const float* __restrict__ x, const float* __restrict__ v,
    const float* __restrict__ resting,
    float* __restrict__ y, float* __restrict__ vout, float* __restrict__ rout,
    const uint64_t* __restrict__ cand, const uint32_t* __restrict__ counter,
    uint32_t cap)
{
    __shared__ uint64_t s[SORT_MAX];
    uint32_t n = *counter;
    if (n > cap) n = cap;
    if (n > SORT_MAX) n = SORT_MAX;

    uint32_t m = 1;
    while (m < n) m <<= 1;
    if (m < 2) m = 2;

    for (uint32_t i = threadIdx.x; i < m; i += BLOCK)
        s[i] = (i < n) ? cand[i] : 0ull;   // 0 sorts last (all real keys have MSB context > 0)
    __syncthreads();

    // bitonic sort, descending
    for (uint32_t kk = 2; kk <= m; kk <<= 1) {
        for (uint32_t j = kk >> 1; j > 0; j >>= 1) {
            for (uint32_t i = threadIdx.x; i < m; i += BLOCK) {
                uint32_t ixj = i ^ j;
                if (ixj > i) {
                    uint64_t a = s[i], b = s[ixj];
                    bool up = (i & kk) == 0;
                    if (up ? (a < b) : (a > b)) { s[i] = b; s[ixj] = a; }
                }
            }
            __syncthreads();
        }
    }

    uint32_t kw = n < K_TOP ? n : K_TOP;
    if (threadIdx.x < kw) {
        uint64_t p = s[threadIdx.x];
        uint32_t idx = ~(uint32_t)p;
        float vv = v[idx];
        float vn = vv + (x[idx] - vv) * 0.5f;
        float r = resting[idx];
        if (vn > 1.0f && r == 0.0f) {
            y[idx]    = 1.0f;
            vout[idx] = 0.0f;
            rout[idx] = 4.0f;   // resting_after = 5.0, then decremented
        }
    }
}

extern "C" void kernel_launch(void* const* d_in, const int* in_sizes, int n_in,
                              void* d_out, int out_size, void* d_ws, size_t ws_size,
                              hipStream_t stream) {
    const float* x       = (const float*)d_in[0];
    const float* v       = (const float*)d_in[1];
    const float* resting = (const float*)d_in[2];
    int n = in_sizes[0];

    float* y    = (float*)d_out;
    float* vout = y + n;
    float* rout = y + 2 * (size_t)n;

    uint32_t* ws       = (uint32_t*)d_ws;
    uint32_t* counter  = ws;            // [0]
    uint32_t* hist     = ws + 16;
    int nchunk = (n + CHUNK - 1) / CHUNK;
    uint32_t* chunkmax = ws + 16 + NBINS;

    size_t candOffU32 = (size_t)16 + NBINS + nchunk;
    candOffU32 = (candOffU32 + 1) & ~(size_t)1;   // 8-byte align
    uint64_t* cand = (uint64_t*)(ws + candOffU32);
    size_t avail = (ws_size > candOffU32 * 4) ? (ws_size - candOffU32 * 4) / 8 : 0;
    uint32_t cap = (uint32_t)(avail < SORT_MAX ? avail : SORT_MAX);

    int zwords = 16 + NBINS;
    k_zero<<<(zwords + BLOCK - 1) / BLOCK, BLOCK, 0, stream>>>(ws, zwords);
    k_main<<<nchunk, BLOCK, 0, stream>>>(x, v, resting, y, vout, rout, hist, chunkmax, n);
    k_thresh<<<1, BLOCK, 0, stream>>>(hist, ws);
    k_collect<<<nchunk, BLOCK, 0, stream>>>(x, v, chunkmax, ws, cand, counter, n, cap);
    k_select<<<1, BLOCK, 0, stream>>>(x, v, resting, y, vout, rout, cand, counter, cap);
}

// Round 3
// 178.281 us; speedup vs baseline: 1.3043x; 1.3043x over previous
//
#include <hip/hip_runtime.h>
#include <stdint.h>

// Problem constants
#define K_TOP      128
#define NBINS      4096        // top-12-bit radix histogram (over chunkmaxes only)
#define BLOCK      256
#define CHUNK      4096        // elements owned by one block in main/collect pass
#define SORT_MAX   4096        // max candidates sorted in the select kernel (32 KiB LDS)

typedef float f32x4 __attribute__((ext_vector_type(4)));

// ws layout (uint32 view):
//  [0]                 candidate counter
//  [1]                 binLo (threshold key prefix)
//  [16 .. 16+nchunk)   per-chunk max key
//  then (8B aligned)   candidate array of uint64 (key<<32 | ~idx)

__device__ __forceinline__ uint32_t f2key(float f) {
    uint32_t u = __float_as_uint(f);
    return (u & 0x80000000u) ? ~u : (u | 0x80000000u);
}

// Fused: leaky integration, no-fire outputs, per-chunk max key. Pure streaming.
__global__ __launch_bounds__(BLOCK) void k_main(
    const float* __restrict__ x, const float* __restrict__ v,
    const float* __restrict__ resting,
    float* __restrict__ y, float* __restrict__ vout, float* __restrict__ rout,
    uint32_t* __restrict__ chunkmax, int n)
{
    uint32_t mymax = 0u;
    const int base = blockIdx.x * CHUNK;

#pragma unroll
    for (int it = 0; it < CHUNK / (BLOCK * 4); ++it) {
        int i = base + (it * BLOCK + threadIdx.x) * 4;
        if (i + 4 <= n) {
            f32x4 x4 = __builtin_nontemporal_load(reinterpret_cast<const f32x4*>(x + i));
            f32x4 v4 = __builtin_nontemporal_load(reinterpret_cast<const f32x4*>(v + i));
            f32x4 r4 = __builtin_nontemporal_load(reinterpret_cast<const f32x4*>(resting + i));
            f32x4 vo, ro;
#pragma unroll
            for (int c = 0; c < 4; ++c) {
                float xv = x4[c], vv = v4[c], rr = r4[c];
                float vn = vv + (xv - vv) * 0.5f;
                uint32_t key = f2key(vn);
                if (key > mymax) mymax = key;
                bool refr = rr > 0.0f;
                vo[c] = refr ? 0.0f : vn;
                ro[c] = refr ? (rr - 1.0f) : 0.0f;
            }
            f32x4 z4 = {0.f, 0.f, 0.f, 0.f};
            __builtin_nontemporal_store(z4, reinterpret_cast<f32x4*>(y + i));
            __builtin_nontemporal_store(vo, reinterpret_cast<f32x4*>(vout + i));
            __builtin_nontemporal_store(ro, reinterpret_cast<f32x4*>(rout + i));
        } else {
            for (int j = i; j < n && j < i + 4; ++j) {
                float xv = x[j], vv = v[j], rr = resting[j];
                float vn = vv + (xv - vv) * 0.5f;
                uint32_t key = f2key(vn);
                if (key > mymax) mymax = key;
                bool refr = rr > 0.0f;
                y[j] = 0.0f;
                vout[j] = refr ? 0.0f : vn;
                rout[j] = refr ? (rr - 1.0f) : 0.0f;
            }
        }
    }

    // wave shuffle max reduce, then cross-wave via tiny LDS
    for (int off = 32; off > 0; off >>= 1) {
        uint32_t o = __shfl_down(mymax, off);
        if (o > mymax) mymax = o;
    }
    __shared__ uint32_t lmax[BLOCK / 64];
    if ((threadIdx.x & 63) == 0) lmax[threadIdx.x >> 6] = mymax;
    __syncthreads();
    if (threadIdx.x == 0) {
        uint32_t m = lmax[0];
        for (int w = 1; w < BLOCK / 64; ++w)
            if (lmax[w] > m) m = lmax[w];
        chunkmax[blockIdx.x] = m;
    }
}

// Histogram the chunkmaxes; find the bin containing the 128th-largest chunkmax.
// binLo = that bin's floor. Guarantee: m128 <= T (128th largest element), since the
// 128 largest chunkmaxes are 128 distinct elements >= m128. So binLo <= T and every
// top-128 element survives the collect filter. Also zeroes the candidate counter.
__global__ __launch_bounds__(BLOCK) void k_thresh(const uint32_t* __restrict__ chunkmax,
                                                  int nchunk, uint32_t* __restrict__ ws)
{
    __shared__ uint32_t hist[NBINS];
    __shared__ uint32_t ssum[BLOCK];
    for (int i = threadIdx.x; i < NBINS; i += BLOCK) hist[i] = 0u;
    __syncthreads();
    for (int i = threadIdx.x; i < nchunk; i += BLOCK)
        atomicAdd(&hist[chunkmax[i] >> 20], 1u);
    __syncthreads();

    int t = threadIdx.x;
    int hi = NBINS - t * 16;       // this thread's segment: bins [hi-16, hi), descending
    uint32_t s = 0;
    for (int i = 0; i < 16; ++i) s += hist[hi - 1 - i];
    ssum[t] = s;
    __syncthreads();
    if (t == 0) {
        ws[0] = 0u;                // zero candidate counter for k_collect
        uint32_t cum = 0;
        int seg = 0;
        for (; seg < BLOCK; ++seg) {
            if (cum + ssum[seg] >= K_TOP) break;
            cum += ssum[seg];
        }
        uint32_t binLo = 0;
        if (seg < BLOCK) {
            int top = NBINS - seg * 16 - 1;
            int b = top;
            for (; b > top - 16; --b) {
                cum += hist[b];
                if (cum >= K_TOP) break;
            }
            if (b == top - 16) b = top - 15;  // safety (shouldn't happen)
            binLo = ((uint32_t)b) << 20;
        }
        ws[1] = binLo;
    }
}

// Collect candidates (key >= binLo). Chunks whose max is below threshold exit immediately.
__global__ __launch_bounds__(BLOCK) void k_collect(
    const float* __restrict__ x, const float* __restrict__ v,
    const uint32_t* __restrict__ chunkmax, const uint32_t* __restrict__ ws,
    uint64_t* __restrict__ cand, uint32_t* __restrict__ counter,
    int n, uint32_t cap)
{
    uint32_t binLo = ws[1];
    if (chunkmax[blockIdx.x] < binLo) return;
    const int base = blockIdx.x * CHUNK;
#pragma unroll
    for (int it = 0; it < CHUNK / BLOCK; ++it) {
        int i = base + it * BLOCK + threadIdx.x;
        if (i < n) {
            float vv = v[i];
            float vn = vv + (x[i] - vv) * 0.5f;
            uint32_t key = f2key(vn);
            if (key >= binLo) {
                uint32_t p = atomicAdd(counter, 1u);
                if (p < cap) cand[p] = ((uint64_t)key << 32) | (uint32_t)(~(uint32_t)i);
            }
        }
    }
}

// Sort candidates descending by (key, then lowest index); apply fire fixup for top-K.
__global__ __launch_bounds__(BLOCK) void k_select(
    const float* __restrict__ x, const float* __restrict__ v,
    const float* __restrict__ resting,
    float* __restrict__ y, float* __restrict__ vout, float* __restrict__ rout,
    const uint64_t* __restrict__ cand, const uint32_t* __restrict__ counter,
    uint32_t cap)
{
    __shared__ uint64_t s[SORT_MAX];
    uint32_t n = *counter;
    if (n > cap) n = cap;
    if (n > SORT_MAX) n = SORT_MAX;

    uint32_t m = 1;
    while (m < n) m <<= 1;
    if (m < 2) m = 2;

    for (uint32_t i = threadIdx.x; i < m; i += BLOCK)
        s[i] = (i < n) ? cand[i] : 0ull;   // 0 sorts last
    __syncthreads();

    // bitonic sort, descending
    for (uint32_t kk = 2; kk <= m; kk <<= 1) {
        for (uint32_t j = kk >> 1; j > 0; j >>= 1) {
            for (uint32_t i = threadIdx.x; i < m; i += BLOCK) {
                uint32_t ixj = i ^ j;
                if (ixj > i) {
                    uint64_t a = s[i], b = s[ixj];
                    bool up = (i & kk) == 0;
                    if (up ? (a < b) : (a > b)) { s[i] = b; s[ixj] = a; }
                }
            }
            __syncthreads();
        }
    }

    uint32_t kw = n < K_TOP ? n : K_TOP;
    if (threadIdx.x < kw) {
        uint64_t p = s[threadIdx.x];
        uint32_t idx = ~(uint32_t)p;
        float vv = v[idx];
        float vn = vv + (x[idx] - vv) * 0.5f;
        float r = resting[idx];
        if (vn > 1.0f && r == 0.0f) {
            y[idx]    = 1.0f;
            vout[idx] = 0.0f;
            rout[idx] = 4.0f;   // resting_after = 5.0, then decremented
        }
    }
}

extern "C" void kernel_launch(void* const* d_in, const int* in_sizes, int n_in,
                              void* d_out, int out_size, void* d_ws, size_t ws_size,
                              hipStream_t stream) {
    const float* x       = (const float*)d_in[0];
    const float* v       = (const float*)d_in[1];
    const float* resting = (const float*)d_in[2];
    int n = in_sizes[0];

    float* y    = (float*)d_out;
    float* vout = y + n;
    float* rout = y + 2 * (size_t)n;

    uint32_t* ws       = (uint32_t*)d_ws;
    uint32_t* counter  = ws;            // [0]
    int nchunk = (n + CHUNK - 1) / CHUNK;
    uint32_t* chunkmax = ws + 16;

    size_t candOffU32 = (size_t)16 + nchunk;
    candOffU32 = (candOffU32 + 1) & ~(size_t)1;   // 8-byte align
    uint64_t* cand = (uint64_t*)(ws + candOffU32);
    size_t avail = (ws_size > candOffU32 * 4) ? (ws_size - candOffU32 * 4) / 8 : 0;
    uint32_t cap = (uint32_t)(avail < SORT_MAX ? avail : SORT_MAX);

    k_main<<<nchunk, BLOCK, 0, stream>>>(x, v, resting, y, vout, rout, chunkmax, n);
    k_thresh<<<1, BLOCK, 0, stream>>>(chunkmax, nchunk, ws);
    k_collect<<<nchunk, BLOCK, 0, stream>>>(x, v, chunkmax, ws, cand, counter, n, cap);
    k_select<<<1, BLOCK, 0, stream>>>(x, v, resting, y, vout, rout, cand, counter, cap);
}